// Round 6
// baseline (7165.262 us; speedup 1.0000x reference)
//
#include <hip/hip_runtime.h>
#include <math.h>

constexpr int kB = 256;
constexpr int kT = 200;
constexpr int kD = 512;
constexpr int kU = 1024;
constexpr int kG = 4096;   // 4*U

typedef short frag8 __attribute__((ext_vector_type(8)));     // 8 bf16 (4 VGPRs)
typedef float floatx4 __attribute__((ext_vector_type(4)));   // MFMA C/D frag
typedef unsigned short ushort_t;

__device__ __forceinline__ ushort_t f2bf(float f) {
    union { float f; unsigned int u; } v; v.f = f;
    unsigned int r = v.u + 0x7fffu + ((v.u >> 16) & 1u);   // RNE
    return (ushort_t)(r >> 16);
}
__device__ __forceinline__ float bf2f(ushort_t h) {
    union { unsigned int u; float f; } v; v.u = ((unsigned int)h) << 16;
    return v.f;
}

// ---------------------------------------------------------------------------
// Repack [W (K1 rows); Uw (K-K1 rows)] fp32 [*,4096] -> bf16 fragment order.
// Gate-interleaved columns: n_new = 4*j + g  <->  n_old = g*1024 + j.
// frag8 addr (units): ((nb*nkb + kb)*4 + ct)*64 + lane  (verified, absmax 0.0)
// ---------------------------------------------------------------------------
__global__ __launch_bounds__(256)
void repack_weights(const float* __restrict__ W, const float* __restrict__ Uw,
                    int K1, int K, ushort_t* __restrict__ out)
{
    const int nkb = K >> 5;
    const int kb = blockIdx.x % nkb;
    const int nb = blockIdx.x / nkb;
    __shared__ ushort_t tile[2048];
    const int tid = threadIdx.x;
#pragma unroll
    for (int i = 0; i < 8; i++) {
        int idx  = tid + (i << 8);         // 0..2047
        int kl   = idx >> 6;               // 0..31
        int lcol = idx & 63;               // 0..63
        int g  = lcol >> 4;
        int jl = lcol & 15;
        int k  = (kb << 5) + kl;
        int n_old = (g << 10) + (nb << 4) + jl;
        float v = (k < K1) ? W[(long)k * kG + n_old]
                           : Uw[(long)(k - K1) * kG + n_old];
        int n_new_l = (jl << 2) + g;       // local packed column
        int ng = n_new_l >> 4, nl = n_new_l & 15;
        int quad = kl >> 3, e = kl & 7;
        tile[ng * 512 + (quad * 16 + nl) * 8 + e] = f2bf(v);
    }
    __syncthreads();
    long base = ((long)(nb * nkb + kb)) * 2048;
    *(frag8*)&out[base + tid * 8] = *(frag8*)&tile[tid * 8];
}

__global__ __launch_bounds__(256)
void repack_bias(const float* __restrict__ b1, const float* __restrict__ b2,
                 float* __restrict__ o1, float* __restrict__ o2)
{
    int n = blockIdx.x * blockDim.x + threadIdx.x;   // 0..4095
    int n_old = ((n & 3) << 10) + (n >> 2);
    o1[n] = b1[n_old];
    o2[n] = b2[n_old];
}

// One-time embedding gather + fp32->bf16: xbf[b*T+t][d].
__global__ __launch_bounds__(128)
void xgather(const int* __restrict__ tokens, const float* __restrict__ emb,
             ushort_t* __restrict__ xbf)
{
    int bt = blockIdx.x;
    int tok = tokens[bt];
    float4 v = *(const float4*)(emb + (long)tok * kD + threadIdx.x * 4);
    unsigned int lo = ((unsigned int)f2bf(v.y) << 16) | f2bf(v.x);
    unsigned int hi = ((unsigned int)f2bf(v.w) << 16) | f2bf(v.z);
    uint2 p; p.x = lo; p.y = hi;
    *(uint2*)(xbf + (long)bt * kD + threadIdx.x * 4) = p;
}

// ---------------------------------------------------------------------------
// Per-step kernel, round-0 dataflow (barrier-free per-wave loads, register
// double-buffer) at DOUBLE occupancy. Grid (64,4,2) x 256 thr,
// __launch_bounds__(256,2): 512 blocks = 2 blocks/CU = 2 waves/SIMD (round 0
// had 1/SIMD — its 3x latency exposure over the ~10us VMEM floor is the
// target). Block = 64 packed cols (nb = blockIdx.x) x 64 rows (blockIdx.y);
// 4 waves 2x2, wave tile 32x32 (acc[2][2], verified epilogue). No LDS B
// staging, no K-loop barriers: B read per-wave from L2 (weight panels stay
// XCD-pinned: block->XCD = id%8 deterministic, 3.5 MB/XCD < 4 MB L2).
// Register budget: 2 Batch (A[8]+B[8]) = 128 VGPR + acc 16 + addr ~30 ->
// ~175, under the 256 cap, still 8 waves/CU.
// Same per-element kb accumulation order as round 0 -> bitwise-identical.
// ---------------------------------------------------------------------------
struct Batch { frag8 A[8]; frag8 B[8]; };

template<int NKB, int K1KB>
__device__ __forceinline__ void load_batch(int b, Batch& bb,
    const ushort_t* a1p0, const ushort_t* a1p1,
    const ushort_t* a2p0, const ushort_t* a2p1,
    const frag8* wb0, const frag8* wb1)
{
    const int kb0 = b * 4;
#pragma unroll
    for (int u = 0; u < 4; u++) {
        bb.B[u*2+0] = wb0[(kb0 + u) * 256];
        bb.B[u*2+1] = wb1[(kb0 + u) * 256];
    }
    if (kb0 < K1KB) {                              // batches are 4-kb aligned
#pragma unroll
        for (int u = 0; u < 4; u++) {
            bb.A[u*2+0] = *(const frag8*)(a1p0 + (kb0 + u) * 32);
            bb.A[u*2+1] = *(const frag8*)(a1p1 + (kb0 + u) * 32);
        }
    } else {
#pragma unroll
        for (int u = 0; u < 4; u++) {
            bb.A[u*2+0] = *(const frag8*)(a2p0 + (kb0 - K1KB + u) * 32);
            bb.A[u*2+1] = *(const frag8*)(a2p1 + (kb0 - K1KB + u) * 32);
        }
    }
}

__device__ __forceinline__ void mfma_batch(const Batch& bb, floatx4 (&acc)[2][2])
{
#pragma unroll
    for (int u = 0; u < 4; u++)
#pragma unroll
        for (int mi = 0; mi < 2; mi++) {
            acc[mi][0] = __builtin_amdgcn_mfma_f32_16x16x32_bf16(
                bb.A[u*2+mi], bb.B[u*2+0], acc[mi][0], 0, 0, 0);
            acc[mi][1] = __builtin_amdgcn_mfma_f32_16x16x32_bf16(
                bb.A[u*2+mi], bb.B[u*2+1], acc[mi][1], 0, 0, 0);
        }
}

template<int NKB, int K1KB>
__device__ __forceinline__ void step_core(
    const ushort_t* __restrict__ A1, long a1_rs, long a1_off,
    const ushort_t* __restrict__ A2,              // row stride kU
    const ushort_t* __restrict__ Wp,
    const float4* __restrict__ biasP4,
    float* __restrict__ cSt, ushort_t* __restrict__ hOut,
    float* __restrict__ zsw)
{
    const int tid  = threadIdx.x;
    const int lane = tid & 63;
    const int wave = tid >> 6;
    const int wr   = wave >> 1, wc = wave & 1;     // 2x2 wave grid
    const int nb   = blockIdx.x;                   // 64-col superblock 0..63
    const int wrow = (blockIdx.y << 6) + (wr << 5);
    const int kq   = (lane >> 4) << 3;
    const int r0   = wrow + (lane & 15);

    const ushort_t* a1p0 = A1 + (long)r0 * a1_rs + a1_off + kq;
    const ushort_t* a1p1 = A1 + (long)(r0 + 16) * a1_rs + a1_off + kq;
    const ushort_t* a2p0 = A2 + (long)r0 * kU + kq;
    const ushort_t* a2p1 = A2 + (long)(r0 + 16) * kU + kq;

    // B frag8 base for this wave's two 16-col quarters (ct = wc*2, wc*2+1)
    const frag8* wb0 = (const frag8*)Wp + ((long)nb * NKB * 4 + (wc << 1)) * 64 + lane;
    const frag8* wb1 = wb0 + 64;

    floatx4 acc[2][2];
#pragma unroll
    for (int i = 0; i < 2; i++) {
        acc[i][0] = (floatx4){0.f, 0.f, 0.f, 0.f};
        acc[i][1] = (floatx4){0.f, 0.f, 0.f, 0.f};
    }

    constexpr int NBATCH = NKB / 4;                // 16 (L2) / 12 (L1) — even
    Batch X, Y;
    load_batch<NKB, K1KB>(0, X, a1p0, a1p1, a2p0, a2p1, wb0, wb1);
#pragma unroll 1
    for (int b = 0; b < NBATCH; b += 2) {
        load_batch<NKB, K1KB>(b + 1, Y, a1p0, a1p1, a2p0, a2p1, wb0, wb1);
        mfma_batch(X, acc);
        if (b + 2 < NBATCH)
            load_batch<NKB, K1KB>(b + 2, X, a1p0, a1p1, a2p0, a2p1, wb0, wb1);
        mfma_batch(Y, acc);
    }

    // Epilogue: per-wave LDS transpose (intra-wave DS ordering), gates fp32.
    // Verified bit-exact (rounds 1-5); c-state global (round 0).
    const int q = lane >> 4, c16 = lane & 15;
    const int rl0 = lane >> 3, jl = lane & 7;      // jl constant per lane
    const int ub = (nb << 4) + (wc << 3);          // h-unit column base
    const float4 bv = biasP4[ub + jl];
#pragma unroll
    for (int mi = 0; mi < 2; mi++) {
#pragma unroll
        for (int ci = 0; ci < 2; ci++)
#pragma unroll
            for (int r = 0; r < 4; r++)
                zsw[((q << 2) + r) * 36 + (ci << 4) + c16] = acc[mi][ci][r];
#pragma unroll
        for (int ii = 0; ii < 2; ii++) {
            int rowl = rl0 + (ii << 3);
            float4 z4 = *(float4*)&zsw[rowl * 36 + (jl << 2)];
            float zi = z4.x + bv.x, zf = z4.y + bv.y;
            float zg = z4.z + bv.z, zo = z4.w + bv.w;
            float ig = 1.f / (1.f + __expf(-zi));
            float fg = 1.f / (1.f + __expf(-zf));
            float og = 1.f / (1.f + __expf(-zo));
            float gg = 1.f - 2.f / (__expf(2.f * zg) + 1.f);   // tanh
            int m = wrow + (mi << 4) + rowl;
            long cidx = (long)m * kU + ub + jl;
            float cn = fg * cSt[cidx] + ig * gg;
            float tc = 1.f - 2.f / (__expf(2.f * cn) + 1.f);   // tanh
            cSt[cidx] = cn;
            hOut[cidx] = f2bf(og * tc);
        }
    }
}

// grid (64, 4, 2): z=0 -> layer2 step t2=l-1, z=1 -> layer1 step t1=l
__global__ __launch_bounds__(256, 2)
void lstm_merged(int zmask,
    const ushort_t* h1_for2, const ushort_t* h2prev, const ushort_t* W2p,
    const float* b2p, float* c2, ushort_t* h2out,
    const ushort_t* xbf, int t1,
    const ushort_t* h1prev, const ushort_t* W1p,
    const float* b1p, float* c1, ushort_t* h1out)
{
    __shared__ __align__(16) float zs[4][576];     // 9 KB epilogue transpose
    float* zsw = zs[threadIdx.x >> 6];
    if (blockIdx.z == 0) {
        if (!(zmask & 1)) return;
        step_core<64, 32>(h1_for2, kU, 0, h2prev, W2p,
                          (const float4*)b2p, c2, h2out, zsw);
    } else {
        if (!(zmask & 2)) return;
        step_core<48, 16>(xbf, (long)kT * kD, (long)t1 * kD, h1prev, W1p,
                          (const float4*)b1p, c1, h1out, zsw);
    }
}

// out[b] = sigmoid(h[b,:] . Wfc + bfc), h in bf16
__global__ __launch_bounds__(256)
void fc_sigmoid(const ushort_t* __restrict__ h, const float* __restrict__ Wfc,
                const float* __restrict__ bfc, float* __restrict__ out)
{
    int b = blockIdx.x, tid = threadIdx.x;
    float s = 0.f;
    for (int j = tid; j < kU; j += 256) s += bf2f(h[(long)b * kU + j]) * Wfc[j];
    __shared__ float red[4];
    for (int off = 32; off > 0; off >>= 1) s += __shfl_down(s, off, 64);
    if ((tid & 63) == 0) red[tid >> 6] = s;
    __syncthreads();
    if (tid == 0) {
        float t = red[0] + red[1] + red[2] + red[3] + bfc[0];
        out[b] = 1.f / (1.f + expf(-t));
    }
}

extern "C" void kernel_launch(void* const* d_in, const int* in_sizes, int n_in,
                              void* d_out, int out_size, void* d_ws, size_t ws_size,
                              hipStream_t stream)
{
    (void)in_sizes; (void)n_in; (void)out_size; (void)ws_size;

    const int*   tokens = (const int*)d_in[0];
    const float* emb    = (const float*)d_in[1];
    const float* W1     = (const float*)d_in[2];
    const float* U1     = (const float*)d_in[3];
    const float* b1     = (const float*)d_in[4];
    const float* W2     = (const float*)d_in[5];
    const float* U2     = (const float*)d_in[6];
    const float* b2     = (const float*)d_in[7];
    const float* Wfc    = (const float*)d_in[8];
    const float* bfc    = (const float*)d_in[9];
    float* out = (float*)d_out;

    // Workspace: ~86 MB
    ushort_t* W1p = (ushort_t*)d_ws;                       // [1536*4096] bf16
    ushort_t* W2p = W1p + (size_t)1536 * kG;               // [2048*4096] bf16
    float* b1p = (float*)(W2p + (size_t)2048 * kG);        // [4096] f32
    float* b2p = b1p + kG;                                 // [4096] f32
    float* c1  = b2p + kG;                                 // [256*1024] f32
    float* c2  = c1 + (size_t)kB * kU;
    ushort_t* hbuf = (ushort_t*)(c2 + (size_t)kB * kU);    // 4 x [256*1024] bf16
    ushort_t* h1b[2] = { hbuf, hbuf + (size_t)kB * kU };
    ushort_t* h2b[2] = { hbuf + 2 * (size_t)kB * kU, hbuf + 3 * (size_t)kB * kU };
    ushort_t* xbf = hbuf + 4 * (size_t)kB * kU;            // [B*T*512] bf16

    repack_weights<<<48 * 64, 256, 0, stream>>>(W1, U1, 512, 1536, W1p);
    repack_weights<<<64 * 64, 256, 0, stream>>>(W2, U2, 1024, 2048, W2p);
    repack_bias<<<16, 256, 0, stream>>>(b1, b2, b1p, b2p);
    xgather<<<kB * kT, 128, 0, stream>>>(tokens, emb, xbf);
    // zero c1,c2 (fp32) + all h buffers (bf16): contiguous 4 MB
    hipMemsetAsync(c1, 0, (size_t)kB * kU * (2 * 4 + 4 * 2), stream);

    for (int l = 0; l <= kT; l++) {
        int t2 = l - 1, t1 = l;
        int zmask = (t2 >= 0 ? 1 : 0) | (t1 < kT ? 2 : 0);
        lstm_merged<<<dim3(64, 4, 2), 256, 0, stream>>>(zmask,
            h1b[(t2 + 1) & 1], h2b[t2 & 1], W2p, b2p, c2, h2b[(t2 + 1) & 1],
            xbf, t1, h1b[t1 & 1], W1p, b1p, c1, h1b[(t1 + 1) & 1]);
    }

    fc_sigmoid<<<kB, 256, 0, stream>>>(h2b[0], Wfc, bfc, out);
}